// Round 1
// baseline (69.439 us; speedup 1.0000x reference)
//
#include <hip/hip_runtime.h>
#include <math.h>

typedef float f32x2 __attribute__((ext_vector_type(2)));
typedef float f32x4 __attribute__((ext_vector_type(4)));

static __device__ __forceinline__ f32x2 fma2(f32x2 a, f32x2 b, f32x2 c) {
#if __has_builtin(__builtin_elementwise_fma)
  return __builtin_elementwise_fma(a, b, c);
#else
  f32x2 r; r.x = fmaf(a.x, b.x, c.x); r.y = fmaf(a.y, b.y, c.y); return r;
#endif
}

#define MJ 64
#define HID 64

// B layout per joint m (32 floats):
//   [0..8]  = R[m] row-major
//   [9..11] = c[m] = G0 + trans - R*G0
//   [12..14]= trans[m]
//   [15]    = 1.0   (accumulates wsum)
//   [16..31]= wproj_w[:,m]
__global__ void rig_prep(const float* __restrict__ G0, const float* __restrict__ so3,
                         const float* __restrict__ trans, const float* __restrict__ wproj_w,
                         const float* __restrict__ w2,
                         float* __restrict__ B, float* __restrict__ w2T) {
  const int t = threadIdx.x;  // 64 threads
  if (t < MJ) {
    const float ox = so3[3*t+0], oy = so3[3*t+1], oz = so3[3*t+2];
    const float th = sqrtf(ox*ox + oy*oy + oz*oz);
    float R[9];
    if (th < 1e-4f) {
      R[0]=1.f;  R[1]=-oz; R[2]=oy;
      R[3]=oz;   R[4]=1.f; R[5]=-ox;
      R[6]=-oy;  R[7]=ox;  R[8]=1.f;
    } else {
      const float it = 1.f/th;
      const float kx=ox*it, ky=oy*it, kz=oz*it;
      const float s=sinf(th), c=cosf(th), mc=1.f-c;
      R[0]=c+kx*kx*mc;     R[1]=kx*ky*mc-kz*s;  R[2]=kx*kz*mc+ky*s;
      R[3]=ky*kx*mc+kz*s;  R[4]=c+ky*ky*mc;     R[5]=ky*kz*mc-kx*s;
      R[6]=kz*kx*mc-ky*s;  R[7]=kz*ky*mc+kx*s;  R[8]=c+kz*kz*mc;
    }
    const float gx=G0[3*t], gy=G0[3*t+1], gz=G0[3*t+2];
    const float tx=trans[3*t], ty=trans[3*t+1], tz=trans[3*t+2];
    float* Bm = B + t*32;
    #pragma unroll
    for (int i=0;i<9;i++) Bm[i]=R[i];
    Bm[9]  = gx + tx - (R[0]*gx + R[1]*gy + R[2]*gz);
    Bm[10] = gy + ty - (R[3]*gx + R[4]*gy + R[5]*gz);
    Bm[11] = gz + tz - (R[6]*gx + R[7]*gy + R[8]*gz);
    Bm[12]=tx; Bm[13]=ty; Bm[14]=tz;
    Bm[15]=1.0f;
    #pragma unroll
    for (int i=0;i<16;i++) Bm[16+i] = wproj_w[i*MJ + t];
  }
  // w2T[j][o] = w2[o][j]
  for (int j=0;j<HID;j++) w2T[j*HID + t] = w2[t*HID + j];
}

__global__ __launch_bounds__(256)
void rig_main(const float* __restrict__ X0, const float* __restrict__ W,
              const float* __restrict__ B,
              const float* __restrict__ wproj_b,
              const float* __restrict__ w1, const float* __restrict__ b1,
              const float* __restrict__ w2T, const float* __restrict__ b2,
              const float* __restrict__ w3, const float* __restrict__ b3,
              float* __restrict__ out, int Ntot) {
  const int n = blockIdx.x*256 + threadIdx.x;
  if (n >= Ntot) return;

  // ---- skinny GEMM row: acc[0..31] = W[n,:] @ B  (raw, normalize later) ----
  f32x2 acc[16];
  #pragma unroll
  for (int i=0;i<16;i++) acc[i] = (f32x2){0.f, 0.f};

  const f32x4* Wr = reinterpret_cast<const f32x4*>(W + (size_t)n*MJ);
  const f32x2* Bv = reinterpret_cast<const f32x2*>(B);
  #pragma unroll
  for (int m4=0;m4<16;m4++) {
    const f32x4 w4 = Wr[m4];
    #pragma unroll
    for (int q=0;q<4;q++) {
      const float w = w4[q];
      const f32x2 wv = {w, w};
      const f32x2* Bm = Bv + (m4*4+q)*16;   // wave-uniform address -> s_load
      #pragma unroll
      for (int i=0;i<16;i++) acc[i] = fma2(wv, Bm[i], acc[i]);
    }
  }

  float v[32];
  #pragma unroll
  for (int i=0;i<16;i++){ v[2*i]=acc[i].x; v[2*i+1]=acc[i].y; }
  const float inv = 1.0f/(v[15] + 1e-12f);

  float Rb[9];
  #pragma unroll
  for (int i=0;i<9;i++) Rb[i]=v[i]*inv;
  const float cb0=v[9]*inv,  cb1=v[10]*inv, cb2=v[11]*inv;
  const float tb0=v[12]*inv, tb1=v[13]*inv, tb2=v[14]*inv;

  const float x0=X0[3*n+0], x1=X0[3*n+1], x2=X0[3*n+2];
  const float sk0 = fmaf(Rb[0],x0, fmaf(Rb[1],x1, fmaf(Rb[2],x2, cb0)));
  const float sk1 = fmaf(Rb[3],x0, fmaf(Rb[4],x1, fmaf(Rb[5],x2, cb1)));
  const float sk2 = fmaf(Rb[6],x0, fmaf(Rb[7],x1, fmaf(Rb[8],x2, cb2)));
  const float u0=sk0-tb0, u1=sk1-tb1, u2=sk2-tb2;

  float hin[19];
  hin[0] = Rb[0]*u0 + Rb[3]*u1 + Rb[6]*u2;   // Rb^T @ u
  hin[1] = Rb[1]*u0 + Rb[4]*u1 + Rb[7]*u2;
  hin[2] = Rb[2]*u0 + Rb[5]*u1 + Rb[8]*u2;
  #pragma unroll
  for (int i=0;i<16;i++) hin[3+i] = fmaf(v[16+i], inv, wproj_b[i]);

  // ---- MLP: 19 -> 64 (relu) -> 64 (relu) -> 3, fused layer1/layer2 ----
  f32x2 h2[32];
  const f32x2* b2v = reinterpret_cast<const f32x2*>(b2);
  #pragma unroll
  for (int o=0;o<32;o++) h2[o] = b2v[o];

  #pragma unroll 8
  for (int j=0;j<HID;j++) {
    float a = b1[j];
    #pragma unroll
    for (int k=0;k<19;k++) a = fmaf(hin[k], w1[j*19+k], a);
    a = fmaxf(a, 0.f);
    const f32x2 a2 = {a, a};
    const f32x2* wrow = reinterpret_cast<const f32x2*>(w2T + j*HID);
    #pragma unroll
    for (int o=0;o<32;o++) h2[o] = fma2(a2, wrow[o], h2[o]);
  }

  #pragma unroll
  for (int o=0;o<32;o++) {
    h2[o].x = fmaxf(h2[o].x, 0.f);
    h2[o].y = fmaxf(h2[o].y, 0.f);
  }

  const f32x2* w3v = reinterpret_cast<const f32x2*>(w3);
  f32x2 s0={0.f,0.f}, s1={0.f,0.f}, s2={0.f,0.f};
  #pragma unroll
  for (int o=0;o<32;o++) {
    s0 = fma2(h2[o], w3v[o],      s0);
    s1 = fma2(h2[o], w3v[32+o],   s1);
    s2 = fma2(h2[o], w3v[64+o],   s2);
  }
  const float d0 = s0.x+s0.y + b3[0];
  const float d1 = s1.x+s1.y + b3[1];
  const float d2 = s2.x+s2.y + b3[2];

  const float dw0 = Rb[0]*d0 + Rb[1]*d1 + Rb[2]*d2;
  const float dw1 = Rb[3]*d0 + Rb[4]*d1 + Rb[5]*d2;
  const float dw2 = Rb[6]*d0 + Rb[7]*d1 + Rb[8]*d2;

  out[3*n+0] = sk0 + dw0;
  out[3*n+1] = sk1 + dw1;
  out[3*n+2] = sk2 + dw2;
}

extern "C" void kernel_launch(void* const* d_in, const int* in_sizes, int n_in,
                              void* d_out, int out_size, void* d_ws, size_t ws_size,
                              hipStream_t stream) {
  const float* X0      = (const float*)d_in[0];
  const float* G0      = (const float*)d_in[1];
  const float* W       = (const float*)d_in[2];
  const float* so3     = (const float*)d_in[3];
  const float* trans   = (const float*)d_in[4];
  const float* wproj_w = (const float*)d_in[5];
  const float* wproj_b = (const float*)d_in[6];
  const float* w1      = (const float*)d_in[7];
  const float* b1      = (const float*)d_in[8];
  const float* w2      = (const float*)d_in[9];
  const float* b2      = (const float*)d_in[10];
  const float* w3      = (const float*)d_in[11];
  const float* b3      = (const float*)d_in[12];
  float* out = (float*)d_out;

  const int Ntot = in_sizes[0] / 3;

  float* B   = (float*)d_ws;          // 64*32 floats
  float* w2T = B + 64*32;             // 64*64 floats

  rig_prep<<<1, 64, 0, stream>>>(G0, so3, trans, wproj_w, w2, B, w2T);
  rig_main<<<(Ntot + 255)/256, 256, 0, stream>>>(X0, W, B, wproj_b,
                                                 w1, b1, w2T, b2, w3, b3,
                                                 out, Ntot);
}